// Round 1
// baseline (1285.685 us; speedup 1.0000x reference)
//
#include <hip/hip_runtime.h>
#include <hip/hip_bf16.h>

#define B_  32
#define H_  8
#define L_  4096
#define D_  64
#define BH_ 256
#define U_  45
#define UP_ 48

typedef float f32x4  __attribute__((ext_vector_type(4)));
typedef short bf16x8 __attribute__((ext_vector_type(8)));

__device__ __forceinline__ unsigned short f2bf(float f) {
  unsigned u = __builtin_bit_cast(unsigned, f);
  u += 0x7fffu + ((u >> 16) & 1u);   // RNE; inputs finite
  return (unsigned short)(u >> 16);
}

// ---------------------------------------------------------------------------
// Kernel 1: M[bh][q] = max_j(Q·K[idx_j]) - mean_j(Q·K[idx_j]), f64 accumulate.
// Quad (4 lanes) per query, each lane covers 16 of 64 dims (coalesced 64B
// per lane-group). XCD-affine bh ordering for L2 locality of the K gather.
// ---------------------------------------------------------------------------
__global__ __launch_bounds__(256) void k_probM(
    const float* __restrict__ Qg, const float* __restrict__ Kg,
    const int* __restrict__ idxg, float* __restrict__ Mg)
{
  const int blk   = blockIdx.x;          // 16384 blocks
  const int xcd   = blk & 7;
  const int rr    = blk >> 3;
  const int bhi   = rr >> 6;             // 0..31
  const int chunk = rr & 63;             // 0..63
  const int bh    = xcd + (bhi << 3);    // XCD-affine: each XCD walks its bh's sequentially
  const int quad  = threadIdx.x >> 2;
  const int lq    = threadIdx.x & 3;
  const int q     = chunk * 64 + quad;

  const float* qrow = Qg + ((size_t)bh * L_ + q) * D_ + lq * 16;
  double qd[16];
#pragma unroll
  for (int c = 0; c < 4; c++) {
    f32x4 v = *(const f32x4*)(qrow + 4 * c);
    qd[4*c+0] = (double)v[0]; qd[4*c+1] = (double)v[1];
    qd[4*c+2] = (double)v[2]; qd[4*c+3] = (double)v[3];
  }

  const float* kb = Kg + (size_t)bh * L_ * D_ + lq * 16;
  const int*   ip = idxg + q * U_;

  double mx = -1e300, sm = 0.0;
  for (int j = 0; j < U_; j++) {
    const float* kr = kb + (size_t)ip[j] * D_;
    double acc = 0.0;
#pragma unroll
    for (int c = 0; c < 4; c++) {
      f32x4 v = *(const f32x4*)(kr + 4 * c);
      acc += qd[4*c+0] * (double)v[0];
      acc += qd[4*c+1] * (double)v[1];
      acc += qd[4*c+2] * (double)v[2];
      acc += qd[4*c+3] * (double)v[3];
    }
    acc += __shfl_xor(acc, 1);
    acc += __shfl_xor(acc, 2);
    mx = fmax(mx, acc);
    sm += acc;
  }
  if (lq == 0) Mg[(size_t)bh * L_ + q] = (float)(mx - sm / 45.0);
}

// ---------------------------------------------------------------------------
// Kernel 2: top-45 indices per (b,h) via 45 iterative block argmax passes.
// Writes 48 entries (3 pads = sels[0], harmlessly recomputed in k_attn).
// ---------------------------------------------------------------------------
__global__ __launch_bounds__(256) void k_top45(
    const float* __restrict__ Mg, int* __restrict__ qselg)
{
  __shared__ float mv[L_];
  __shared__ float rv[256];
  __shared__ int   ri[256];
  __shared__ int   sels[UP_];
  const int bh = blockIdx.x, t = threadIdx.x;

  for (int i = t; i < L_; i += 256) mv[i] = Mg[(size_t)bh * L_ + i];
  __syncthreads();

  for (int it = 0; it < U_; it++) {
    float bv = -3.4e38f; int bi = 0;
    for (int i = t; i < L_; i += 256) {
      float v = mv[i];
      if (v > bv) { bv = v; bi = i; }
    }
    rv[t] = bv; ri[t] = bi;
    __syncthreads();
    for (int s = 128; s > 0; s >>= 1) {
      if (t < s) {
        float ov = rv[t + s];
        if (ov > rv[t] || (ov == rv[t] && ri[t + s] < ri[t])) {
          rv[t] = ov; ri[t] = ri[t + s];
        }
      }
      __syncthreads();
    }
    if (t == 0) { sels[it] = ri[0]; mv[ri[0]] = -3.4e38f; }
    __syncthreads();
  }
  if (t == 0) { sels[45] = sels[0]; sels[46] = sels[0]; sels[47] = sels[0]; }
  __syncthreads();
  if (t < UP_) qselg[bh * UP_ + t] = sels[t];
}

// ---------------------------------------------------------------------------
// Kernel 3: context = cumsum(V, axis=L), written transposed to out[b,l,h,d].
// 8 L-segments x 64 dims per block; two-pass (seg sums -> prefixed scan).
// ---------------------------------------------------------------------------
__global__ __launch_bounds__(512) void k_cumsum(
    const float* __restrict__ Vg, float* __restrict__ out)
{
  const int bh = blockIdx.x, b = bh >> 3, h = bh & 7;
  const int d = threadIdx.x & 63, s = threadIdx.x >> 6;   // 8 segs x 512 rows
  __shared__ float segsum[8][64];

  const float* vb = Vg + (size_t)bh * L_ * D_ + d;
  const int l0 = s * 512;

  float acc = 0.f;
  for (int l = l0; l < l0 + 512; l += 4) {
    float a0 = vb[(size_t)(l + 0) * D_];
    float a1 = vb[(size_t)(l + 1) * D_];
    float a2 = vb[(size_t)(l + 2) * D_];
    float a3 = vb[(size_t)(l + 3) * D_];
    acc += a0; acc += a1; acc += a2; acc += a3;
  }
  segsum[s][d] = acc;
  __syncthreads();

  float run = 0.f;
  for (int ss = 0; ss < s; ss++) run += segsum[ss][d];

  float* ob = out + ((size_t)b * L_ * H_ + h) * D_ + d;
  for (int l = l0; l < l0 + 512; l += 4) {
    float a0 = vb[(size_t)(l + 0) * D_];
    float a1 = vb[(size_t)(l + 1) * D_];
    float a2 = vb[(size_t)(l + 2) * D_];
    float a3 = vb[(size_t)(l + 3) * D_];
    run += a0; ob[(size_t)(l + 0) * (H_ * D_)] = run;
    run += a1; ob[(size_t)(l + 1) * (H_ * D_)] = run;
    run += a2; ob[(size_t)(l + 2) * (H_ * D_)] = run;
    run += a3; ob[(size_t)(l + 3) * (H_ * D_)] = run;
  }
}

// ---------------------------------------------------------------------------
// Kernel 4: flash attention for the 45 selected rows per (b,h), bf16 MFMA.
// 8 waves split the 4096 keys (512 each); per-wave online softmax; P is
// moved C-frag -> A-frag through a padded per-wave LDS buffer; deterministic
// barrier-serialized cross-wave combine; overwrite rows of `out`.
// mask value -1e30; dead-row guard: p *= (m_row > -1e29).
// ---------------------------------------------------------------------------
__global__ __launch_bounds__(512, 2) void k_attn(
    const float* __restrict__ Qg, const float* __restrict__ Kg,
    const float* __restrict__ Vg, const int* __restrict__ qselg,
    float* __restrict__ out)
{
  const int bh = blockIdx.x, b = bh >> 3, h = bh & 7;
  const int wave = threadIdx.x >> 6, lane = threadIdx.x & 63;
  const int l15 = lane & 15, l4 = lane >> 4;

  __shared__ int   qs[UP_];
  __shared__ float mw[8][UP_];
  __shared__ float lw[8][UP_];
  __shared__ float lgf[UP_];
  __shared__ float Osum[UP_][64];
  __shared__ unsigned short Pl[8][16][72];   // per-wave P tile, padded stride 72

  if (threadIdx.x < UP_) qs[threadIdx.x] = qselg[bh * UP_ + threadIdx.x];
  for (int i = threadIdx.x; i < UP_ * 64; i += 512) (&Osum[0][0])[i] = 0.f;
  __syncthreads();

  int qmax = 0;
  for (int r2 = 0; r2 < UP_; r2++) qmax = max(qmax, qs[r2]);

  const float* Qb = Qg + (size_t)bh * L_ * D_;
  const float* Kb = Kg + (size_t)bh * L_ * D_;
  const float* Vb = Vg + (size_t)bh * L_ * D_;

  // A-frags: Q rows gathered at qsel. A[row=l15][k=(l4)*8+j]
  bf16x8 aq[3][2];
#pragma unroll
  for (int mf = 0; mf < 3; mf++) {
    const float* src = Qb + (size_t)qs[mf * 16 + l15] * D_ + l4 * 8;
#pragma unroll
    for (int ks = 0; ks < 2; ks++) {
      bf16x8 a;
#pragma unroll
      for (int j = 0; j < 8; j++) a[j] = (short)f2bf(src[ks * 32 + j]);
      aq[mf][ks] = a;
    }
  }

  int myq[3][4];
#pragma unroll
  for (int mf = 0; mf < 3; mf++)
#pragma unroll
    for (int rg = 0; rg < 4; rg++)
      myq[mf][rg] = qs[mf * 16 + l4 * 4 + rg];

  float m_r[3][4], l_r[3][4];
  f32x4 Oa[3][4];
  const f32x4 z4 = {0.f, 0.f, 0.f, 0.f};
#pragma unroll
  for (int mf = 0; mf < 3; mf++)
#pragma unroll
    for (int rg = 0; rg < 4; rg++) { m_r[mf][rg] = -1e30f; l_r[mf][rg] = 0.f; }
#pragma unroll
  for (int mf = 0; mf < 3; mf++)
#pragma unroll
    for (int df = 0; df < 4; df++) Oa[mf][df] = z4;

  for (int t = 0; t < 8; t++) {
    const int k0 = wave * 512 + t * 64;
    if (k0 > qmax) break;   // k0 ascending per wave; uniform within wave

    // ---- S = (Q K^T): B[kdim=d][col=key] = K[key][d]
    f32x4 S[3][4];
#pragma unroll
    for (int nf = 0; nf < 4; nf++) {
      const float* ksrc = Kb + (size_t)(k0 + nf * 16 + l15) * D_ + l4 * 8;
      bf16x8 bk0, bk1;
#pragma unroll
      for (int j = 0; j < 8; j++) bk0[j] = (short)f2bf(ksrc[j]);
#pragma unroll
      for (int j = 0; j < 8; j++) bk1[j] = (short)f2bf(ksrc[32 + j]);
#pragma unroll
      for (int mf = 0; mf < 3; mf++) {
        f32x4 c = z4;
        c = __builtin_amdgcn_mfma_f32_16x16x32_bf16(aq[mf][0], bk0, c, 0, 0, 0);
        c = __builtin_amdgcn_mfma_f32_16x16x32_bf16(aq[mf][1], bk1, c, 0, 0, 0);
        S[mf][nf] = c;
      }
    }

    // ---- scale + causal mask (col > qsel[row] -> -1e30)
#pragma unroll
    for (int mf = 0; mf < 3; mf++)
#pragma unroll
      for (int nf = 0; nf < 4; nf++) {
        const int kc = k0 + nf * 16 + l15;
#pragma unroll
        for (int rg = 0; rg < 4; rg++) {
          float v = S[mf][nf][rg] * 0.125f;
          S[mf][nf][rg] = (kc > myq[mf][rg]) ? -1e30f : v;
        }
      }

    // ---- V B-frags for this tile (shared across mf)
    bf16x8 vv[2][4];
#pragma unroll
    for (int ks = 0; ks < 2; ks++)
#pragma unroll
      for (int df = 0; df < 4; df++) {
        bf16x8 x;
#pragma unroll
        for (int j = 0; j < 8; j++)
          x[j] = (short)f2bf(Vb[(size_t)(k0 + ks * 32 + l4 * 8 + j) * D_ + df * 16 + l15]);
        vv[ks][df] = x;
      }

#pragma unroll
    for (int mf = 0; mf < 3; mf++) {
      // online-softmax stats update (row lives in 16 consecutive lanes)
#pragma unroll
      for (int rg = 0; rg < 4; rg++) {
        float tm = fmax(fmax(S[mf][0][rg], S[mf][1][rg]),
                        fmax(S[mf][2][rg], S[mf][3][rg]));
#pragma unroll
        for (int off = 1; off < 16; off <<= 1) tm = fmax(tm, __shfl_xor(tm, off));
        const float mn = fmax(m_r[mf][rg], tm);
        const float sc = __expf(m_r[mf][rg] - mn);   // (-1e30)-(-1e30)=0 -> 1
        l_r[mf][rg] *= sc;
#pragma unroll
        for (int df = 0; df < 4; df++) Oa[mf][df][rg] *= sc;
        m_r[mf][rg] = mn;
      }

      // p = exp(S - m), dead-row guarded; write P tile (C-layout) to LDS
      float rs[4] = {0.f, 0.f, 0.f, 0.f};
#pragma unroll
      for (int nf = 0; nf < 4; nf++)
#pragma unroll
        for (int rg = 0; rg < 4; rg++) {
          float p = __expf(S[mf][nf][rg] - m_r[mf][rg]);
          p = (m_r[mf][rg] > -1e29f) ? p : 0.f;
          rs[rg] += p;
          Pl[wave][l4 * 4 + rg][nf * 16 + l15] = f2bf(p);
        }
#pragma unroll
      for (int rg = 0; rg < 4; rg++) {
        float r = rs[rg];
#pragma unroll
        for (int off = 1; off < 16; off <<= 1) r += __shfl_xor(r, off);
        l_r[mf][rg] += r;
      }

      // PV: A-frag read back from LDS (row=l15, k=(l4)*8+j), accumulate O
#pragma unroll
      for (int ks = 0; ks < 2; ks++) {
        const bf16x8 pa = *(const bf16x8*)(&Pl[wave][l15][ks * 32 + l4 * 8]);
#pragma unroll
        for (int df = 0; df < 4; df++)
          Oa[mf][df] = __builtin_amdgcn_mfma_f32_16x16x32_bf16(pa, vv[ks][df], Oa[mf][df], 0, 0, 0);
      }
    }
  }

  // ---- cross-wave combine (deterministic)
  if (l15 == 0) {
#pragma unroll
    for (int mf = 0; mf < 3; mf++)
#pragma unroll
      for (int rg = 0; rg < 4; rg++) {
        const int row = mf * 16 + l4 * 4 + rg;
        mw[wave][row] = m_r[mf][rg];
        lw[wave][row] = l_r[mf][rg];
      }
  }
  __syncthreads();

  float sc_me[3][4];
#pragma unroll
  for (int mf = 0; mf < 3; mf++)
#pragma unroll
    for (int rg = 0; rg < 4; rg++) {
      const int row = mf * 16 + l4 * 4 + rg;
      float m = -1e30f;
#pragma unroll
      for (int w = 0; w < 8; w++) m = fmax(m, mw[w][row]);
      float ls = 0.f;
#pragma unroll
      for (int w = 0; w < 8; w++) ls += lw[w][row] * __expf(mw[w][row] - m);
      sc_me[mf][rg] = __expf(m_r[mf][rg] - m);   // 0 for dead waves
      if (wave == 0 && l15 == 0) lgf[row] = ls;
    }

  for (int w = 0; w < 8; w++) {
    __syncthreads();
    if (wave == w) {
#pragma unroll
      for (int mf = 0; mf < 3; mf++)
#pragma unroll
        for (int df = 0; df < 4; df++)
#pragma unroll
          for (int rg = 0; rg < 4; rg++)
            Osum[mf * 16 + l4 * 4 + rg][df * 16 + l15] += Oa[mf][df][rg] * sc_me[mf][rg];
    }
  }
  __syncthreads();

  for (int i = threadIdx.x; i < U_ * 64; i += 512) {
    const int r = i >> 6, d = i & 63;
    out[(((size_t)b * L_ + (size_t)qs[r]) * H_ + h) * D_ + d] = Osum[r][d] / lgf[r];
  }
}

// ---------------------------------------------------------------------------
extern "C" void kernel_launch(void* const* d_in, const int* in_sizes, int n_in,
                              void* d_out, int out_size, void* d_ws, size_t ws_size,
                              hipStream_t stream)
{
  const float* Q   = (const float*)d_in[0];
  const float* K   = (const float*)d_in[1];
  const float* V   = (const float*)d_in[2];
  const int*   idx = (const int*)d_in[3];
  float* out = (float*)d_out;

  const size_t m_bytes = (size_t)BH_ * L_ * sizeof(float);   // 4 MiB
  float* M    = (float*)d_ws;
  int*   qsel = (int*)((char*)d_ws + m_bytes);
  if (ws_size < m_bytes + (size_t)BH_ * UP_ * sizeof(int)) return;

  k_probM <<<16384, 256, 0, stream>>>(Q, K, idx, M);
  k_top45 <<<BH_,   256, 0, stream>>>(M, qsel);
  k_cumsum<<<BH_,   512, 0, stream>>>(V, out);
  k_attn  <<<BH_,   512, 0, stream>>>(Q, K, V, qsel, out);
}